// Round 5
// baseline (4035.246 us; speedup 1.0000x reference)
//
#include <hip/hip_runtime.h>

#define NB 512   // encoder grid; partials need NB*64*4 = 128 KB of ws

typedef float v2f __attribute__((ext_vector_type(2)));
static __device__ __forceinline__ v2f splat(float s) { v2f r; r.x = s; r.y = s; return r; }
static __device__ __forceinline__ v2f vfma(v2f a, v2f b, v2f c) {
    return __builtin_elementwise_fma(a, b, c);
}
static __device__ __forceinline__ v2f vmaxz(v2f a) {
    v2f z; z.x = 0.0f; z.y = 0.0f;
    return __builtin_elementwise_max(a, z);
}

// ---------------- atomic-mode prologue (only if ws too small) ----------------
__global__ __launch_bounds__(64) void prep_kernel(unsigned int* __restrict__ g)
{
    g[threadIdx.x & 63] = 0u;
}

// ---------- encoder: per-point MLP 2->16->32->64, channel max ----------
// R4 post-mortem: ANY partial unroll makes vmax/h2 dynamically-indexed ->
// scratch (VGPR=96, WRITE 183MB). Full unroll everywhere; weights from LDS
// (broadcast ds_read_b128, 0 conflicts); P=2 points/thread sharing each
// weight read; v_pk_fma_f32 via ext_vector_type(2).
__global__ __launch_bounds__(256) void encoder_kernel(
    const float* __restrict__ x,   // [3 + 2N]
    const float* __restrict__ c1w, const float* __restrict__ c1b,
    const float* __restrict__ c2w, const float* __restrict__ c2b,
    const float* __restrict__ c3w, const float* __restrict__ c3b,
    float* __restrict__ ws, int N, int use_atomic)
{
    __shared__ __align__(16) float sW2[512];    // 32x16
    __shared__ __align__(16) float sW3[2048];   // 64x32
    __shared__ float sW1[32], sB1[16], sB2[32], sB3[64];
    __shared__ float wred[4 * 64];
    int t = threadIdx.x;

    if (t < 32) sW1[t] = c1w[t];
    if (t < 16) sB1[t] = c1b[t];
    if (t < 32) sB2[t] = c2b[t];
    if (t < 64) sB3[t] = c3b[t];
    for (int i = t; i < 512; i += 256)  sW2[i] = c2w[i];
    for (int i = t; i < 2048; i += 256) sW3[i] = c3w[i];
    __syncthreads();

    const float4* __restrict__ W2v = (const float4*)sW2;
    const float4* __restrict__ W3v = (const float4*)sW3;

    float vmax[64];
#pragma unroll
    for (int c = 0; c < 64; c++) vmax[c] = 0.0f;   // ReLU outputs >= 0

    const int stride = NB * 256;        // grid stride (one P=2 pair per thread)
#pragma unroll 1
    for (int p0 = blockIdx.x * 256 + t; p0 < N; p0 += 2 * stride) {
        int p1 = p0 + stride;
        if (p1 >= N) p1 = p0;           // duplicate point: max unchanged
        v2f px, py;
        px.x = x[3 + p0];     px.y = x[3 + p1];
        py.x = x[3 + N + p0]; py.y = x[3 + N + p1];

        v2f h1[16];
#pragma unroll
        for (int c = 0; c < 16; c++)
            h1[c] = vmaxz(vfma(splat(sW1[2 * c]), px,
                          vfma(splat(sW1[2 * c + 1]), py, splat(sB1[c]))));

        v2f h2[32];
#pragma unroll
        for (int c = 0; c < 32; c++) {
            v2f a = splat(sB2[c]);
#pragma unroll
            for (int q = 0; q < 4; q++) {
                float4 w = W2v[c * 4 + q];
                a = vfma(splat(w.x), h1[4 * q], a);
                a = vfma(splat(w.y), h1[4 * q + 1], a);
                a = vfma(splat(w.z), h1[4 * q + 2], a);
                a = vfma(splat(w.w), h1[4 * q + 3], a);
            }
            h2[c] = vmaxz(a);
        }

#pragma unroll
        for (int c = 0; c < 64; c++) {
            v2f a = splat(sB3[c]);
#pragma unroll
            for (int q = 0; q < 8; q++) {
                float4 w = W3v[c * 8 + q];
                a = vfma(splat(w.x), h2[4 * q], a);
                a = vfma(splat(w.y), h2[4 * q + 1], a);
                a = vfma(splat(w.z), h2[4 * q + 2], a);
                a = vfma(splat(w.w), h2[4 * q + 3], a);
            }
            // relu folded into running max (vmax >= 0 always)
            vmax[c] = fmaxf(vmax[c], fmaxf(a.x, a.y));
        }
    }

    // wave butterfly (64 lanes)
#pragma unroll
    for (int c = 0; c < 64; c++) {
        float v = vmax[c];
#pragma unroll
        for (int off = 32; off > 0; off >>= 1)
            v = fmaxf(v, __shfl_xor(v, off, 64));
        vmax[c] = v;
    }

    int wid = t >> 6, lane = t & 63;
    if (lane == 0) {
#pragma unroll
        for (int c = 0; c < 64; c++) wred[wid * 64 + c] = vmax[c];
    }
    __syncthreads();
    if (t < 64) {
        float m = fmaxf(fmaxf(wred[t], wred[64 + t]),
                        fmaxf(wred[128 + t], wred[192 + t]));
        if (use_atomic)
            atomicMax((unsigned int*)ws + t, __float_as_uint(m)); // valid: m >= 0
        else
            ws[blockIdx.x * 64 + t] = m;
    }
}

// ---------- tail: feat reduce + everything after, one 1024-thread block ----------
__global__ __launch_bounds__(1024) void tail_kernel(
    const float* __restrict__ x,
    const float* __restrict__ hx,  const float* __restrict__ cx,
    const float* __restrict__ fcw, const float* __restrict__ fcb,
    const float* __restrict__ o1w, const float* __restrict__ o1b,
    const float* __restrict__ o2w, const float* __restrict__ o2b,
    const float* __restrict__ pw,  const float* __restrict__ pb,
    const float* __restrict__ wih, const float* __restrict__ whh,
    const float* __restrict__ bih, const float* __restrict__ bhh,
    const float* __restrict__ q1w, const float* __restrict__ q1b,
    const float* __restrict__ q2w, const float* __restrict__ q2b,
    const float* __restrict__ aw1, const float* __restrict__ ab1,
    const float* __restrict__ aw2, const float* __restrict__ ab2,
    const float* __restrict__ ciw1, const float* __restrict__ cib1,
    const float* __restrict__ ciw2, const float* __restrict__ cib2,
    const float* __restrict__ cew1, const float* __restrict__ ceb1,
    const float* __restrict__ cew2, const float* __restrict__ ceb2,
    const float* __restrict__ ws, int nb, int use_atomic,
    float* __restrict__ out)
{
    __shared__ float feat[64], obs[64], sig8[8], pose[8], z[128], hnew[128];
    __shared__ float zp1s[64], zp2s[64], a1s[16], cih[16], ceh[16], logits[5];
    __shared__ float odom[3], wred2[256], gpart[1024], shx[128];
    int t = threadIdx.x;

    if (t < 3)   odom[t] = x[t];
    if (t < 128) shx[t] = hx[t];
    // reduce per-block partials (or read atomic gmax)
    if (t < 256) {
        int c = t & 63, g = t >> 6;
        float m = 0.0f;
        if (use_atomic) {
            if (g == 0) m = __uint_as_float(((const unsigned int*)ws)[c]);
        } else {
            for (int i = g; i < nb; i += 4) m = fmaxf(m, ws[i * 64 + c]);
        }
        wred2[t] = m;
    }
    __syncthreads();
    if (t < 64)
        feat[t] = fmaxf(fmaxf(wred2[t], wred2[64 + t]),
                        fmaxf(wred2[128 + t], wred2[192 + t]));
    __syncthreads();

    if (t < 64) {                       // obs = fcw @ feat + fcb
        float a = fcb[t];
        for (int k = 0; k < 64; k++) a = fmaf(fcw[t * 64 + k], feat[k], a);
        obs[t] = a;
    } else if (t < 72) {                // sig8 = sigmoid(o1w @ odom + o1b)
        int r = t - 64;
        float a = o1b[r];
        for (int k = 0; k < 3; k++) a = fmaf(o1w[r * 3 + k], odom[k], a);
        sig8[r] = 1.0f / (1.0f + expf(-a));
    }
    __syncthreads();

    if (t < 8) {                        // pose = relu(o2w @ sig8 + o2b)
        float a = o2b[t];
        for (int k = 0; k < 8; k++) a = fmaf(o2w[t * 8 + k], sig8[k], a);
        pose[t] = fmaxf(a, 0.0f);
    }
    __syncthreads();

    if (t < 128) {                      // z = relu(pw @ [obs;pose] + pb)
        float a = pb[t];
        for (int k = 0; k < 64; k++) a = fmaf(pw[t * 72 + k], obs[k], a);
        for (int k = 0; k < 8; k++)  a = fmaf(pw[t * 72 + 64 + k], pose[k], a);
        z[t] = fmaxf(a, 0.0f);
    }
    __syncthreads();

    // LSTM gate partials: t<512 -> wih row t against z; t>=512 -> whh row vs shx
    {
        int r = t & 511, half = t >> 9;
        float a;
        if (half == 0) {
            a = bih[r];
            const float4* w4 = (const float4*)(wih + (size_t)r * 128);
#pragma unroll 4
            for (int q = 0; q < 32; q++) {
                float4 w = w4[q];
                a = fmaf(w.x, z[4 * q], fmaf(w.y, z[4 * q + 1],
                    fmaf(w.z, z[4 * q + 2], fmaf(w.w, z[4 * q + 3], a))));
            }
        } else {
            a = bhh[r];
            const float4* w4 = (const float4*)(whh + (size_t)r * 128);
#pragma unroll 4
            for (int q = 0; q < 32; q++) {
                float4 w = w4[q];
                a = fmaf(w.x, shx[4 * q], fmaf(w.y, shx[4 * q + 1],
                    fmaf(w.z, shx[4 * q + 2], fmaf(w.w, shx[4 * q + 3], a))));
            }
        }
        gpart[t] = a;
    }
    __syncthreads();

    if (t < 128) {                      // LSTM cell update
        float gI = gpart[t]       + gpart[512 + t];
        float gF = gpart[128 + t] + gpart[640 + t];
        float gG = gpart[256 + t] + gpart[768 + t];
        float gO = gpart[384 + t] + gpart[896 + t];
        float ig = 1.0f / (1.0f + expf(-gI));
        float fg = 1.0f / (1.0f + expf(-gF));
        float gg = tanhf(gG);
        float og = 1.0f / (1.0f + expf(-gO));
        float cn = fg * cx[t] + ig * gg;
        float hn = og * tanhf(cn);
        hnew[t] = hn;
        out[7 + t]   = hn;              // hx2
        out[135 + t] = cn;              // cx2
    }
    __syncthreads();

    if (t < 64) {                       // zp1 = relu(q1w @ h_new + q1b)
        float a = q1b[t];
        const float4* w4 = (const float4*)(q1w + (size_t)t * 128);
#pragma unroll 4
        for (int q = 0; q < 32; q++) {
            float4 w = w4[q];
            a = fmaf(w.x, hnew[4 * q], fmaf(w.y, hnew[4 * q + 1],
                fmaf(w.z, hnew[4 * q + 2], fmaf(w.w, hnew[4 * q + 3], a))));
        }
        zp1s[t] = fmaxf(a, 0.0f);
    }
    __syncthreads();

    if (t < 64) {                       // zp2 = relu(q2w @ zp1 + q2b)
        float a = q2b[t];
        for (int k = 0; k < 64; k++) a = fmaf(q2w[t * 64 + k], zp1s[k], a);
        zp2s[t] = fmaxf(a, 0.0f);
    }
    __syncthreads();

    if (t < 16) {
        float a = ab1[t];
        for (int k = 0; k < 64; k++) a = fmaf(aw1[t * 64 + k], zp2s[k], a);
        a1s[t] = fmaxf(a, 0.0f);
    } else if (t < 32) {
        int r = t - 16;
        float a = cib1[r];
        for (int k = 0; k < 64; k++) a = fmaf(ciw1[r * 64 + k], zp2s[k], a);
        cih[r] = fmaxf(a, 0.0f);
    } else if (t < 48) {
        int r = t - 32;
        float a = ceb1[r];
        for (int k = 0; k < 64; k++) a = fmaf(cew1[r * 64 + k], zp2s[k], a);
        ceh[r] = fmaxf(a, 0.0f);
    }
    __syncthreads();

    if (t < 5) {
        float a = ab2[t];
        for (int k = 0; k < 16; k++) a = fmaf(aw2[t * 16 + k], a1s[k], a);
        logits[t] = a;
    } else if (t == 5) {                // ci
        float a = cib2[0];
        for (int k = 0; k < 16; k++) a = fmaf(ciw2[k], cih[k], a);
        out[5] = a;
    } else if (t == 6) {                // ce
        float a = ceb2[0];
        for (int k = 0; k < 16; k++) a = fmaf(cew2[k], ceh[k], a);
        out[6] = a;
    }
    if (t >= 8 && t < 16) out[263 + (t - 8)] = pose[t - 8];  // pose
    __syncthreads();

    if (t == 0) {                       // softmax over 5 logits
        float m = logits[0];
        for (int i = 1; i < 5; i++) m = fmaxf(m, logits[i]);
        float e[5], s = 0.0f;
        for (int i = 0; i < 5; i++) { e[i] = expf(logits[i] - m); s += e[i]; }
        for (int i = 0; i < 5; i++) out[i] = e[i] / s;
    }
}

extern "C" void kernel_launch(void* const* d_in, const int* in_sizes, int n_in,
                              void* d_out, int out_size, void* d_ws, size_t ws_size,
                              hipStream_t stream)
{
    const float* x    = (const float*)d_in[0];
    const float* hx   = (const float*)d_in[1];
    const float* cx   = (const float*)d_in[2];
    const float* c1w  = (const float*)d_in[3];
    const float* c1b  = (const float*)d_in[4];
    const float* c2w  = (const float*)d_in[5];
    const float* c2b  = (const float*)d_in[6];
    const float* c3w  = (const float*)d_in[7];
    const float* c3b  = (const float*)d_in[8];
    const float* fcw  = (const float*)d_in[9];
    const float* fcb  = (const float*)d_in[10];
    const float* o1w  = (const float*)d_in[11];
    const float* o1b  = (const float*)d_in[12];
    const float* o2w  = (const float*)d_in[13];
    const float* o2b  = (const float*)d_in[14];
    const float* pw   = (const float*)d_in[15];
    const float* pb   = (const float*)d_in[16];
    const float* wih  = (const float*)d_in[17];
    const float* whh  = (const float*)d_in[18];
    const float* bih  = (const float*)d_in[19];
    const float* bhh  = (const float*)d_in[20];
    const float* q1w  = (const float*)d_in[21];
    const float* q1b  = (const float*)d_in[22];
    const float* q2w  = (const float*)d_in[23];
    const float* q2b  = (const float*)d_in[24];
    const float* aw1  = (const float*)d_in[25];
    const float* ab1  = (const float*)d_in[26];
    const float* aw2  = (const float*)d_in[27];
    const float* ab2  = (const float*)d_in[28];
    const float* ciw1 = (const float*)d_in[29];
    const float* cib1 = (const float*)d_in[30];
    const float* ciw2 = (const float*)d_in[31];
    const float* cib2 = (const float*)d_in[32];
    const float* cew1 = (const float*)d_in[33];
    const float* ceb1 = (const float*)d_in[34];
    const float* cew2 = (const float*)d_in[35];
    const float* ceb2 = (const float*)d_in[36];

    int N = (in_sizes[0] - 3) / 2;
    int use_atomic = (ws_size < (size_t)(NB * 64 * 4)) ? 1 : 0;

    if (use_atomic)
        prep_kernel<<<1, 64, 0, stream>>>((unsigned int*)d_ws);
    encoder_kernel<<<NB, 256, 0, stream>>>(x, c1w, c1b, c2w, c2b, c3w, c3b,
                                           (float*)d_ws, N, use_atomic);
    tail_kernel<<<1, 1024, 0, stream>>>(x, hx, cx, fcw, fcb, o1w, o1b, o2w, o2b,
                                        pw, pb, wih, whh, bih, bhh, q1w, q1b,
                                        q2w, q2b, aw1, ab1, aw2, ab2, ciw1, cib1,
                                        ciw2, cib2, cew1, ceb1, cew2, ceb2,
                                        (const float*)d_ws, NB, use_atomic,
                                        (float*)d_out);
}

// Round 6
// 202.047 us; speedup vs baseline: 19.9718x; 19.9718x over previous
//
#include <hip/hip_runtime.h>

#define NBLK 1024   // encoder grid; partials path needs NBLK*64*4 = 256 KB of ws

typedef __attribute__((ext_vector_type(8))) short bf16x8;
typedef __attribute__((ext_vector_type(4))) float f32x4;

union U4 { unsigned int u[4]; bf16x8 v; };

static __device__ __forceinline__ unsigned int pack_bf16(float lo, float hi) {
    // truncation; inputs of layer casts are bf16-exact so lossless there
    return (__float_as_uint(hi) & 0xFFFF0000u) | (__float_as_uint(lo) >> 16);
}

// ---------------- atomic-mode prologue (only if ws too small) ----------------
// 0x007FFFFF == monotone-uint encoding of -inf
__global__ __launch_bounds__(64) void prep_kernel(unsigned int* __restrict__ g)
{
    g[threadIdx.x & 63] = 0x007FFFFFu;
}

// ---------- encoder: per-point MLP 2->16->32->64 via MFMA, channel max ----------
// b3 bias + relu deferred past the max (monotone); vmax tracks RAW layer-3 out.
__global__ __launch_bounds__(256) void encoder_kernel(
    const float* __restrict__ x,   // [3 + 2N]
    const float* __restrict__ c1w, const float* __restrict__ c1b,
    const float* __restrict__ c2w, const float* __restrict__ c2b,
    const float* __restrict__ c3w,
    float* __restrict__ ws, int N, int use_atomic)
{
    __shared__ float sW1x[16], sW1y[16], sB1s[16];
    __shared__ float sW2[512], sB2[32];
    __shared__ float sW3[2048];
    __shared__ unsigned int sh2[4 * 272];   // per-wave 16 rows x 17 dwords
    __shared__ float wred[4 * 64];

    int t = threadIdx.x;
    if (t < 16) { sW1x[t] = c1w[2 * t]; sW1y[t] = c1w[2 * t + 1]; sB1s[t] = c1b[t]; }
    if (t < 32) sB2[t] = c2b[t];
    for (int i = t; i < 512; i += 256)  sW2[i] = c2w[i];
    for (int i = t; i < 2048; i += 256) sW3[i] = c3w[i];
    __syncthreads();

    const int lane = t & 63, wid = t >> 6;
    const int n16 = lane & 15, q = lane >> 4;

    // A-fragments: A[m=lane&15][k=q*8+j]
    bf16x8 a2[2];                       // W2 (32x16), K zero-padded to 32
#pragma unroll
    for (int tt = 0; tt < 2; ++tt)
#pragma unroll
        for (int j = 0; j < 8; ++j) {
            int k = q * 8 + j;
            float w = (k < 16) ? sW2[(tt * 16 + n16) * 16 + k] : 0.0f;
            a2[tt][j] = (short)(__float_as_uint(w) >> 16);
        }
    bf16x8 a3[4];                       // W3 (64x32), K=32 exact
#pragma unroll
    for (int tt = 0; tt < 4; ++tt)
#pragma unroll
        for (int j = 0; j < 8; ++j) {
            float w = sW3[(tt * 16 + n16) * 32 + q * 8 + j];
            a3[tt][j] = (short)(__float_as_uint(w) >> 16);
        }
    float w1x[8], w1y[8], b1v[8];       // layer-1 rows for this lane's k-slice
#pragma unroll
    for (int j = 0; j < 8; ++j) {
        int k = q * 8 + j;
        if (k < 16) { w1x[j] = sW1x[k]; w1y[j] = sW1y[k]; b1v[j] = sB1s[k]; }
        else        { w1x[j] = 0.f;     w1y[j] = 0.f;     b1v[j] = 0.f; }
    }
    float b2a[4], b2b[4];
#pragma unroll
    for (int r = 0; r < 4; ++r) { b2a[r] = sB2[q * 4 + r]; b2b[r] = sB2[16 + q * 4 + r]; }

    float vmax[16];
#pragma unroll
    for (int i = 0; i < 16; ++i) vmax[i] = -INFINITY;

    unsigned int* hb = sh2 + wid * 272;
    const int WPG = NBLK * 4;
    const int gw = blockIdx.x * 4 + wid;
    const int niter = (N + WPG * 16 - 1) / (WPG * 16);

    int p = gw * 16 + n16; if (p >= N) p = N - 1;
    float px = x[3 + p], py = x[3 + N + p];

#pragma unroll 1
    for (int it = 0; it < niter; ++it) {
        float cpx = px, cpy = py;
        if (it + 1 < niter) {           // prefetch next tile's point
            int pn = ((it + 1) * WPG + gw) * 16 + n16;
            if (pn >= N) pn = N - 1;
            px = x[3 + pn]; py = x[3 + N + pn];
        }

        // ----- layer 1 -> B-fragment (bf16, k = q*8+j, zeros for k>=16) -----
        unsigned int h1d0 = 0, h1d1 = 0, h1d2 = 0, h1d3 = 0;
        if (q < 2) {
            float h0 = fmaxf(fmaf(w1x[0], cpx, fmaf(w1y[0], cpy, b1v[0])), 0.f);
            float h1 = fmaxf(fmaf(w1x[1], cpx, fmaf(w1y[1], cpy, b1v[1])), 0.f);
            float h2 = fmaxf(fmaf(w1x[2], cpx, fmaf(w1y[2], cpy, b1v[2])), 0.f);
            float h3 = fmaxf(fmaf(w1x[3], cpx, fmaf(w1y[3], cpy, b1v[3])), 0.f);
            float h4 = fmaxf(fmaf(w1x[4], cpx, fmaf(w1y[4], cpy, b1v[4])), 0.f);
            float h5 = fmaxf(fmaf(w1x[5], cpx, fmaf(w1y[5], cpy, b1v[5])), 0.f);
            float h6 = fmaxf(fmaf(w1x[6], cpx, fmaf(w1y[6], cpy, b1v[6])), 0.f);
            float h7 = fmaxf(fmaf(w1x[7], cpx, fmaf(w1y[7], cpy, b1v[7])), 0.f);
            h1d0 = pack_bf16(h0, h1); h1d1 = pack_bf16(h2, h3);
            h1d2 = pack_bf16(h4, h5); h1d3 = pack_bf16(h6, h7);
        }
        U4 bu; bu.u[0] = h1d0; bu.u[1] = h1d1; bu.u[2] = h1d2; bu.u[3] = h1d3;

        // ----- layer 2: 2 MFMAs, rows 0-15 / 16-31 -----
        f32x4 z4 = {0.f, 0.f, 0.f, 0.f};
        f32x4 acc2a = __builtin_amdgcn_mfma_f32_16x16x32_bf16(a2[0], bu.v, z4, 0, 0, 0);
        f32x4 acc2b = __builtin_amdgcn_mfma_f32_16x16x32_bf16(a2[1], bu.v, z4, 0, 0, 0);

        // ----- bias+relu, D-layout -> B-layout via per-wave LDS transpose -----
        // lane holds channels q*4+r (a) and 16+q*4+r (b) of point n16
        unsigned int base = (unsigned int)(n16 * 17);
        hb[base + 2 * q]     = pack_bf16(fmaxf(acc2a[0] + b2a[0], 0.f),
                                         fmaxf(acc2a[1] + b2a[1], 0.f));
        hb[base + 2 * q + 1] = pack_bf16(fmaxf(acc2a[2] + b2a[2], 0.f),
                                         fmaxf(acc2a[3] + b2a[3], 0.f));
        hb[base + 8 + 2 * q] = pack_bf16(fmaxf(acc2b[0] + b2b[0], 0.f),
                                         fmaxf(acc2b[1] + b2b[1], 0.f));
        hb[base + 9 + 2 * q] = pack_bf16(fmaxf(acc2b[2] + b2b[2], 0.f),
                                         fmaxf(acc2b[3] + b2b[3], 0.f));
        __builtin_amdgcn_s_waitcnt(0xc07f);   // lgkmcnt(0): same-wave LDS RAW
        U4 ru;
        ru.u[0] = hb[base + 4 * q];     ru.u[1] = hb[base + 4 * q + 1];
        ru.u[2] = hb[base + 4 * q + 2]; ru.u[3] = hb[base + 4 * q + 3];

        // ----- layer 3: 4 MFMAs (64 rows), raw output -> running max -----
        f32x4 o0 = __builtin_amdgcn_mfma_f32_16x16x32_bf16(a3[0], ru.v, z4, 0, 0, 0);
        f32x4 o1 = __builtin_amdgcn_mfma_f32_16x16x32_bf16(a3[1], ru.v, z4, 0, 0, 0);
        f32x4 o2 = __builtin_amdgcn_mfma_f32_16x16x32_bf16(a3[2], ru.v, z4, 0, 0, 0);
        f32x4 o3 = __builtin_amdgcn_mfma_f32_16x16x32_bf16(a3[3], ru.v, z4, 0, 0, 0);
#pragma unroll
        for (int r = 0; r < 4; ++r) {
            vmax[r]      = fmaxf(vmax[r],      o0[r]);
            vmax[4 + r]  = fmaxf(vmax[4 + r],  o1[r]);
            vmax[8 + r]  = fmaxf(vmax[8 + r],  o2[r]);
            vmax[12 + r] = fmaxf(vmax[12 + r], o3[r]);
        }
    }

    // reduce across the 16 point-lanes (n16 dimension)
#pragma unroll
    for (int i = 0; i < 16; ++i) {
        float v = vmax[i];
        v = fmaxf(v, __shfl_xor(v, 1, 64));
        v = fmaxf(v, __shfl_xor(v, 2, 64));
        v = fmaxf(v, __shfl_xor(v, 4, 64));
        v = fmaxf(v, __shfl_xor(v, 8, 64));
        vmax[i] = v;
    }
    if (n16 == 0) {
        // lane (q, n16=0): vmax[tt*4+r] is channel tt*16 + q*4 + r
#pragma unroll
        for (int tt = 0; tt < 4; ++tt)
#pragma unroll
            for (int r = 0; r < 4; ++r)
                wred[wid * 64 + tt * 16 + q * 4 + r] = vmax[tt * 4 + r];
    }
    __syncthreads();
    if (t < 64) {
        float m = fmaxf(fmaxf(wred[t], wred[64 + t]),
                        fmaxf(wred[128 + t], wred[192 + t]));
        if (use_atomic) {
            unsigned int b = __float_as_uint(m);
            unsigned int e = (b & 0x80000000u) ? ~b : (b | 0x80000000u);
            atomicMax((unsigned int*)ws + t, e);
        } else {
            ws[blockIdx.x * 64 + t] = m;
        }
    }
}

// ---------- tail: feat reduce (+b3+relu) + everything after, one block ----------
__global__ __launch_bounds__(1024) void tail_kernel(
    const float* __restrict__ x,
    const float* __restrict__ hx,  const float* __restrict__ cx,
    const float* __restrict__ c3b,
    const float* __restrict__ fcw, const float* __restrict__ fcb,
    const float* __restrict__ o1w, const float* __restrict__ o1b,
    const float* __restrict__ o2w, const float* __restrict__ o2b,
    const float* __restrict__ pw,  const float* __restrict__ pb,
    const float* __restrict__ wih, const float* __restrict__ whh,
    const float* __restrict__ bih, const float* __restrict__ bhh,
    const float* __restrict__ q1w, const float* __restrict__ q1b,
    const float* __restrict__ q2w, const float* __restrict__ q2b,
    const float* __restrict__ aw1, const float* __restrict__ ab1,
    const float* __restrict__ aw2, const float* __restrict__ ab2,
    const float* __restrict__ ciw1, const float* __restrict__ cib1,
    const float* __restrict__ ciw2, const float* __restrict__ cib2,
    const float* __restrict__ cew1, const float* __restrict__ ceb1,
    const float* __restrict__ cew2, const float* __restrict__ ceb2,
    const float* __restrict__ ws, int nb, int use_atomic,
    float* __restrict__ out)
{
    __shared__ float feat[64], obs[64], sig8[8], pose[8], z[128], hnew[128];
    __shared__ float zp1s[64], zp2s[64], a1s[16], cih[16], ceh[16], logits[5];
    __shared__ float odom[3], wred2[256], gpart[1024], shx[128];
    int t = threadIdx.x;

    if (t < 3)   odom[t] = x[t];
    if (t < 128) shx[t] = hx[t];
    if (t < 256) {
        int c = t & 63, g = t >> 6;
        float m = -INFINITY;
        if (use_atomic) {
            if (g == 0) {
                unsigned int u = ((const unsigned int*)ws)[c];
                unsigned int b = (u & 0x80000000u) ? (u ^ 0x80000000u) : ~u;
                m = __uint_as_float(b);
            }
        } else {
            for (int i = g; i < nb; i += 4) m = fmaxf(m, ws[i * 64 + c]);
        }
        wred2[t] = m;
    }
    __syncthreads();
    if (t < 64) {
        float raw = fmaxf(fmaxf(wred2[t], wred2[64 + t]),
                          fmaxf(wred2[128 + t], wred2[192 + t]));
        feat[t] = fmaxf(raw + c3b[t], 0.0f);   // deferred layer-3 bias + relu
    }
    __syncthreads();

    if (t < 64) {                       // obs = fcw @ feat + fcb
        float a = fcb[t];
        for (int k = 0; k < 64; k++) a = fmaf(fcw[t * 64 + k], feat[k], a);
        obs[t] = a;
    } else if (t < 72) {                // sig8 = sigmoid(o1w @ odom + o1b)
        int r = t - 64;
        float a = o1b[r];
        for (int k = 0; k < 3; k++) a = fmaf(o1w[r * 3 + k], odom[k], a);
        sig8[r] = 1.0f / (1.0f + expf(-a));
    }
    __syncthreads();

    if (t < 8) {                        // pose = relu(o2w @ sig8 + o2b)
        float a = o2b[t];
        for (int k = 0; k < 8; k++) a = fmaf(o2w[t * 8 + k], sig8[k], a);
        pose[t] = fmaxf(a, 0.0f);
    }
    __syncthreads();

    if (t < 128) {                      // z = relu(pw @ [obs;pose] + pb)
        float a = pb[t];
        for (int k = 0; k < 64; k++) a = fmaf(pw[t * 72 + k], obs[k], a);
        for (int k = 0; k < 8; k++)  a = fmaf(pw[t * 72 + 64 + k], pose[k], a);
        z[t] = fmaxf(a, 0.0f);
    }
    __syncthreads();

    // LSTM gate partials: t<512 -> wih row t against z; t>=512 -> whh row vs shx
    {
        int r = t & 511, half = t >> 9;
        float a;
        if (half == 0) {
            a = bih[r];
            const float4* w4 = (const float4*)(wih + (size_t)r * 128);
#pragma unroll 4
            for (int qq = 0; qq < 32; qq++) {
                float4 w = w4[qq];
                a = fmaf(w.x, z[4 * qq], fmaf(w.y, z[4 * qq + 1],
                    fmaf(w.z, z[4 * qq + 2], fmaf(w.w, z[4 * qq + 3], a))));
            }
        } else {
            a = bhh[r];
            const float4* w4 = (const float4*)(whh + (size_t)r * 128);
#pragma unroll 4
            for (int qq = 0; qq < 32; qq++) {
                float4 w = w4[qq];
                a = fmaf(w.x, shx[4 * qq], fmaf(w.y, shx[4 * qq + 1],
                    fmaf(w.z, shx[4 * qq + 2], fmaf(w.w, shx[4 * qq + 3], a))));
            }
        }
        gpart[t] = a;
    }
    __syncthreads();

    if (t < 128) {                      // LSTM cell update
        float gI = gpart[t]       + gpart[512 + t];
        float gF = gpart[128 + t] + gpart[640 + t];
        float gG = gpart[256 + t] + gpart[768 + t];
        float gO = gpart[384 + t] + gpart[896 + t];
        float ig = 1.0f / (1.0f + expf(-gI));
        float fg = 1.0f / (1.0f + expf(-gF));
        float gg = tanhf(gG);
        float og = 1.0f / (1.0f + expf(-gO));
        float cn = fg * cx[t] + ig * gg;
        float hn = og * tanhf(cn);
        hnew[t] = hn;
        out[7 + t]   = hn;              // hx2
        out[135 + t] = cn;              // cx2
    }
    __syncthreads();

    if (t < 64) {                       // zp1 = relu(q1w @ h_new + q1b)
        float a = q1b[t];
        const float4* w4 = (const float4*)(q1w + (size_t)t * 128);
#pragma unroll 4
        for (int qq = 0; qq < 32; qq++) {
            float4 w = w4[qq];
            a = fmaf(w.x, hnew[4 * qq], fmaf(w.y, hnew[4 * qq + 1],
                fmaf(w.z, hnew[4 * qq + 2], fmaf(w.w, hnew[4 * qq + 3], a))));
        }
        zp1s[t] = fmaxf(a, 0.0f);
    }
    __syncthreads();

    if (t < 64) {                       // zp2 = relu(q2w @ zp1 + q2b)
        float a = q2b[t];
        for (int k = 0; k < 64; k++) a = fmaf(q2w[t * 64 + k], zp1s[k], a);
        zp2s[t] = fmaxf(a, 0.0f);
    }
    __syncthreads();

    if (t < 16) {
        float a = ab1[t];
        for (int k = 0; k < 64; k++) a = fmaf(aw1[t * 64 + k], zp2s[k], a);
        a1s[t] = fmaxf(a, 0.0f);
    } else if (t < 32) {
        int r = t - 16;
        float a = cib1[r];
        for (int k = 0; k < 64; k++) a = fmaf(ciw1[r * 64 + k], zp2s[k], a);
        cih[r] = fmaxf(a, 0.0f);
    } else if (t < 48) {
        int r = t - 32;
        float a = ceb1[r];
        for (int k = 0; k < 64; k++) a = fmaf(cew1[r * 64 + k], zp2s[k], a);
        ceh[r] = fmaxf(a, 0.0f);
    }
    __syncthreads();

    if (t < 5) {
        float a = ab2[t];
        for (int k = 0; k < 16; k++) a = fmaf(aw2[t * 16 + k], a1s[k], a);
        logits[t] = a;
    } else if (t == 5) {                // ci
        float a = cib2[0];
        for (int k = 0; k < 16; k++) a = fmaf(ciw2[k], cih[k], a);
        out[5] = a;
    } else if (t == 6) {                // ce
        float a = ceb2[0];
        for (int k = 0; k < 16; k++) a = fmaf(cew2[k], ceh[k], a);
        out[6] = a;
    }
    if (t >= 8 && t < 16) out[263 + (t - 8)] = pose[t - 8];  // pose
    __syncthreads();

    if (t == 0) {                       // softmax over 5 logits
        float m = logits[0];
        for (int i = 1; i < 5; i++) m = fmaxf(m, logits[i]);
        float e[5], s = 0.0f;
        for (int i = 0; i < 5; i++) { e[i] = expf(logits[i] - m); s += e[i]; }
        for (int i = 0; i < 5; i++) out[i] = e[i] / s;
    }
}

extern "C" void kernel_launch(void* const* d_in, const int* in_sizes, int n_in,
                              void* d_out, int out_size, void* d_ws, size_t ws_size,
                              hipStream_t stream)
{
    const float* x    = (const float*)d_in[0];
    const float* hx   = (const float*)d_in[1];
    const float* cx   = (const float*)d_in[2];
    const float* c1w  = (const float*)d_in[3];
    const float* c1b  = (const float*)d_in[4];
    const float* c2w  = (const float*)d_in[5];
    const float* c2b  = (const float*)d_in[6];
    const float* c3w  = (const float*)d_in[7];
    const float* c3b  = (const float*)d_in[8];
    const float* fcw  = (const float*)d_in[9];
    const float* fcb  = (const float*)d_in[10];
    const float* o1w  = (const float*)d_in[11];
    const float* o1b  = (const float*)d_in[12];
    const float* o2w  = (const float*)d_in[13];
    const float* o2b  = (const float*)d_in[14];
    const float* pw   = (const float*)d_in[15];
    const float* pb   = (const float*)d_in[16];
    const float* wih  = (const float*)d_in[17];
    const float* whh  = (const float*)d_in[18];
    const float* bih  = (const float*)d_in[19];
    const float* bhh  = (const float*)d_in[20];
    const float* q1w  = (const float*)d_in[21];
    const float* q1b  = (const float*)d_in[22];
    const float* q2w  = (const float*)d_in[23];
    const float* q2b  = (const float*)d_in[24];
    const float* aw1  = (const float*)d_in[25];
    const float* ab1  = (const float*)d_in[26];
    const float* aw2  = (const float*)d_in[27];
    const float* ab2  = (const float*)d_in[28];
    const float* ciw1 = (const float*)d_in[29];
    const float* cib1 = (const float*)d_in[30];
    const float* ciw2 = (const float*)d_in[31];
    const float* cib2 = (const float*)d_in[32];
    const float* cew1 = (const float*)d_in[33];
    const float* ceb1 = (const float*)d_in[34];
    const float* cew2 = (const float*)d_in[35];
    const float* ceb2 = (const float*)d_in[36];

    int N = (in_sizes[0] - 3) / 2;
    int use_atomic = (ws_size < (size_t)(NBLK * 64 * 4)) ? 1 : 0;

    if (use_atomic)
        prep_kernel<<<1, 64, 0, stream>>>((unsigned int*)d_ws);
    encoder_kernel<<<NBLK, 256, 0, stream>>>(x, c1w, c1b, c2w, c2b, c3w,
                                             (float*)d_ws, N, use_atomic);
    tail_kernel<<<1, 1024, 0, stream>>>(x, hx, cx, c3b, fcw, fcb, o1w, o1b,
                                        o2w, o2b, pw, pb, wih, whh, bih, bhh,
                                        q1w, q1b, q2w, q2b, aw1, ab1, aw2, ab2,
                                        ciw1, cib1, ciw2, cib2, cew1, ceb1,
                                        cew2, ceb2, (const float*)d_ws, NBLK,
                                        use_atomic, (float*)d_out);
}